// Round 13
// baseline (16494.629 us; speedup 1.0000x reference)
//
#include <hip/hip_runtime.h>
#include <stdint.h>

#define V_ 16000
#define E_ 512
#define H_ 1024
#define B_ 32
#define T_ 64
#define NG_ 3072        // 3*H rows per weight matrix
#define NR_ 6144        // virtual rows in gru gemm (ih + hh)
#define TPAD_ 8         // u64 stride per batch token slot
#define NBLK_ 256       // persistent grid = #CUs

typedef float f32x4 __attribute__((ext_vector_type(4)));
typedef unsigned long long u64;

__device__ __forceinline__ unsigned int fkey(float f) {
    unsigned int u = __float_as_uint(f);
    return (u & 0x80000000u) ? ~u : (u | 0x80000000u);
}

// Device-scope sense-reversal grid barrier. All NBLK_ blocks resident by
// construction (LDS > 80KB forces 1 block/CU; grid == #CUs). __syncthreads
// drains each wave's vmcnt (stores in L2); tid0's __threadfence does the
// cross-XCD writeback (release) / invalidate (acquire) per G16.
__device__ __forceinline__ void gbar(unsigned* cnt, unsigned* gen) {
    __syncthreads();
    if (threadIdx.x == 0) {
        __threadfence();
        unsigned g = __hip_atomic_load(gen, __ATOMIC_RELAXED,
                                       __HIP_MEMORY_SCOPE_AGENT);
        unsigned a = __hip_atomic_fetch_add(cnt, 1u, __ATOMIC_ACQ_REL,
                                            __HIP_MEMORY_SCOPE_AGENT);
        if (a == NBLK_ - 1) {
            __hip_atomic_store(cnt, 0u, __ATOMIC_RELAXED,
                               __HIP_MEMORY_SCOPE_AGENT);
            __threadfence();
            __hip_atomic_fetch_add(gen, 1u, __ATOMIC_RELEASE,
                                   __HIP_MEMORY_SCOPE_AGENT);
        } else {
            while (__hip_atomic_load(gen, __ATOMIC_ACQUIRE,
                                     __HIP_MEMORY_SCOPE_AGENT) == g)
                __builtin_amdgcn_s_sleep(2);
        }
        __threadfence();
    }
    __syncthreads();
}

__global__ void init_kernel(const float* __restrict__ hidden,
                            float* __restrict__ h0, float* __restrict__ h1,
                            u64* __restrict__ tokpk, unsigned* __restrict__ bar) {
    int idx = blockIdx.x * blockDim.x + threadIdx.x;
    if (idx < B_ * H_) {
        h0[idx] = hidden[idx];
        h1[idx] = hidden[B_ * H_ + idx];
    }
    if (idx < T_ * B_ * TPAD_) tokpk[idx] = 0ull;
    if (idx == 0) { bar[0] = 0u; bar[1] = 0u; }
}

// ---------------------------------------------------------------------------
// r12-proven 64-row x 32-batch streamed GEMM core, 256 threads, acc[8][8].
// ---------------------------------------------------------------------------
__device__ __forceinline__ void gemm_core64(
    const float* wq0, const float* wq1, const float* wq2, const float* wq3,
    const float* aq0, const float* aq1,
    int dW0, int dW1, int dW2, int dW3, int dA0, int dA1,
    int nch, float* lds, int tid, float acc[8][8])
{
    const int ks = tid >> 5, pos = tid & 31;
    const int rg = pos >> 2, bgp = pos & 3;

    f32x4 w0 = *(const f32x4*)wq0, w1 = *(const f32x4*)wq1;
    f32x4 w2 = *(const f32x4*)wq2, w3 = *(const f32x4*)wq3;
    f32x4 a0 = *(const f32x4*)aq0, a1 = *(const f32x4*)aq1;
    *(f32x4*)&lds[dW0] = w0; *(f32x4*)&lds[dW1] = w1;
    *(f32x4*)&lds[dW2] = w2; *(f32x4*)&lds[dW3] = w3;
    *(f32x4*)&lds[dA0] = a0; *(f32x4*)&lds[dA1] = a1;
    __syncthreads();

    int cur = 0;
    for (int c = 0; c < nch; c++) {
        if (c + 1 < nch) {
            const int o = (c + 1) << 6;
            w0 = *(const f32x4*)(wq0 + o); w1 = *(const f32x4*)(wq1 + o);
            w2 = *(const f32x4*)(wq2 + o); w3 = *(const f32x4*)(wq3 + o);
            a0 = *(const f32x4*)(aq0 + o); a1 = *(const f32x4*)(aq1 + o);
        }
        const float* Wb = &lds[cur * 6144];
        const float* Ab = Wb + 4096;
        #pragma unroll
        for (int kk = 0; kk < 2; kk++) {
            const int k4 = ks * 2 + kk;
            f32x4 ww[8], ha[8];
            #pragma unroll
            for (int vi = 0; vi < 8; vi++) {
                const int row = rg + 8 * vi;           // row&7 == rg
                ww[vi] = *(const f32x4*)&Wb[(row << 6) + ((k4 ^ rg) << 2)];
            }
            #pragma unroll
            for (int j = 0; j < 8; j++) {
                const int br = bgp + 4 * j;
                ha[j] = *(const f32x4*)&Ab[(br << 6) + ((k4 ^ (br & 7)) << 2)];
            }
            #pragma unroll
            for (int vi = 0; vi < 8; vi++)
                #pragma unroll
                for (int j = 0; j < 8; j++)
                    acc[vi][j] += ww[vi].x*ha[j].x + ww[vi].y*ha[j].y
                                + ww[vi].z*ha[j].z + ww[vi].w*ha[j].w;
        }
        if (c + 1 < nch) {
            float* L = &lds[(cur ^ 1) * 6144];
            *(f32x4*)&L[dW0] = w0; *(f32x4*)&L[dW1] = w1;
            *(f32x4*)&L[dW2] = w2; *(f32x4*)&L[dW3] = w3;
            *(f32x4*)&L[dA0] = a0; *(f32x4*)&L[dA1] = a1;
        }
        __syncthreads();
        cur ^= 1;
    }
}

__device__ __forceinline__ void reduce_totl(float* lds, int tid, float acc[8][8])
{
    const int ks = tid >> 5, pos = tid & 31;
    {
        float* dst = &lds[(ks * 32 + pos) * 68];
        #pragma unroll
        for (int vi = 0; vi < 8; vi++) {
            f32x4 p0 = {acc[vi][0], acc[vi][1], acc[vi][2], acc[vi][3]};
            f32x4 p1 = {acc[vi][4], acc[vi][5], acc[vi][6], acc[vi][7]};
            *(f32x4*)&dst[vi * 8]     = p0;
            *(f32x4*)&dst[vi * 8 + 4] = p1;
        }
    }
    __syncthreads();
    const int vi2 = tid >> 5, pos2 = tid & 31;
    f32x4 s0 = {0.f, 0.f, 0.f, 0.f}, s1 = {0.f, 0.f, 0.f, 0.f};
    #pragma unroll
    for (int k = 0; k < 8; k++) {
        const float* src = &lds[(k * 32 + pos2) * 68 + vi2 * 8];
        s0 += *(const f32x4*)src;
        s1 += *(const f32x4*)(src + 4);
    }
    __syncthreads();
    const int row = (pos2 >> 2) + 8 * vi2;   // 0..63
    const int bb  = pos2 & 3;                // batch = bb + 4*j
    lds[(bb +  0) * 68 + row] = s0.x;
    lds[(bb +  4) * 68 + row] = s0.y;
    lds[(bb +  8) * 68 + row] = s0.z;
    lds[(bb + 12) * 68 + row] = s0.w;
    lds[(bb + 16) * 68 + row] = s1.x;
    lds[(bb + 20) * 68 + row] = s1.y;
    lds[(bb + 24) * 68 + row] = s1.z;
    lds[(bb + 28) * 68 + row] = s1.w;
    __syncthreads();
}

// GRU GEMM phase body (r12 gemm_gru, blockIdx -> blk param). blk in [0,192).
__device__ __forceinline__ void gru_gemm_phase(
    int blk0, int tid, float* lds,
    const float* Wih, const float* Whh, int Kih,
    const float* xbase, int xld,
    const float* embed, const u64* tokprev, int t, int tmode,
    const float* hprev, float* gbuf)
{
    const int kslice = blk0 >= 96 ? 1 : 0;
    const int tile = blk0 - kslice * 96;
    const int k4s = tid & 15;
    const int rr  = tid >> 4;                // 0..15

    const float* Wbase; int K, n0, nout;
    const float *ar0, *ar1;
    if (tile < 48) {
        n0 = tile * 64; nout = n0; Wbase = Wih; K = Kih;
        if (tmode) {
            int tok0 = 0, tok1 = 0;
            if (t > 0) {
                tok0 = (int)(0xFFFFFFFFu -
                       (unsigned)(tokprev[(size_t)rr * TPAD_] & 0xFFFFFFFFull));
                tok1 = (int)(0xFFFFFFFFu -
                       (unsigned)(tokprev[(size_t)(rr + 16) * TPAD_] & 0xFFFFFFFFull));
            }
            ar0 = embed + (size_t)tok0 * Kih;
            ar1 = embed + (size_t)tok1 * Kih;
        } else {
            ar0 = xbase + (size_t)rr * xld;
            ar1 = xbase + (size_t)(rr + 16) * xld;
        }
    } else {
        n0 = (tile - 48) * 64; nout = NG_ + n0; Wbase = Whh; K = H_;
        ar0 = hprev + (size_t)rr * H_;
        ar1 = hprev + (size_t)(rr + 16) * H_;
    }
    const int koff = kslice * (K >> 1);
    const int nch  = K >> 7;                 // 4 or 8 chunks

    const float *wq0, *wq1, *wq2, *wq3;
    int dW0, dW1, dW2, dW3;
    {
        const int r0 = rr, r1 = 16 + rr, r2 = 32 + rr, r3 = 48 + rr;
        wq0 = Wbase + (size_t)(n0 + r0) * K + koff + k4s * 4;
        wq1 = Wbase + (size_t)(n0 + r1) * K + koff + k4s * 4;
        wq2 = Wbase + (size_t)(n0 + r2) * K + koff + k4s * 4;
        wq3 = Wbase + (size_t)(n0 + r3) * K + koff + k4s * 4;
        dW0 = (r0 << 6) + ((k4s ^ (r0 & 7)) << 2);
        dW1 = (r1 << 6) + ((k4s ^ (r1 & 7)) << 2);
        dW2 = (r2 << 6) + ((k4s ^ (r2 & 7)) << 2);
        dW3 = (r3 << 6) + ((k4s ^ (r3 & 7)) << 2);
    }
    const float* aq0 = ar0 + koff + k4s * 4;
    const float* aq1 = ar1 + koff + k4s * 4;
    const int dA0 = 4096 + (rr << 6) + ((k4s ^ (rr & 7)) << 2);
    const int dA1 = 4096 + ((rr + 16) << 6) + ((k4s ^ (rr & 7)) << 2);

    float acc[8][8] = {};
    gemm_core64(wq0, wq1, wq2, wq3, aq0, aq1,
                dW0, dW1, dW2, dW3, dA0, dA1, nch, lds, tid, acc);
    reduce_totl(lds, tid, acc);

    {
        const int b = tid >> 3, seg = tid & 7;
        float* gout = gbuf + (size_t)kslice * B_ * NR_
                    + (size_t)b * NR_ + nout + seg * 8;
        f32x4 x0 = *(f32x4*)&lds[b * 68 + seg * 8];
        f32x4 x1 = *(f32x4*)&lds[b * 68 + seg * 8 + 4];
        *(f32x4*)gout = x0;
        *(f32x4*)(gout + 4) = x1;
    }
}

// Combine phase: 32768 elems over 256 blocks x 128 active threads.
__device__ __forceinline__ void combine_phase(
    int blk, int tid, const float* gbuf,
    const float* bih, const float* bhh,
    const float* hprev, float* hnew)
{
    if (tid >= 128) return;
    const int idx = blk * 128 + tid;          // 0..32767
    const int b = idx >> 10, i = idx & 1023;
    const float* gb0 = gbuf + (size_t)b * NR_;
    const float* gb1 = gbuf + (size_t)(B_ + b) * NR_;
    const float gir = gb0[i]         + gb1[i];
    const float giz = gb0[H_ + i]    + gb1[H_ + i];
    const float gin = gb0[2*H_ + i]  + gb1[2*H_ + i];
    const float ghr = gb0[NG_ + i]        + gb1[NG_ + i];
    const float ghz = gb0[NG_ + H_ + i]   + gb1[NG_ + H_ + i];
    const float ghn = gb0[NG_ + 2*H_ + i] + gb1[NG_ + 2*H_ + i];
    const float Sr = gir + ghr + bih[i] + bhh[i];
    const float Sz = giz + ghz + bih[H_ + i] + bhh[H_ + i];
    const float rr = 1.f / (1.f + expf(-Sr));
    const float zz = 1.f / (1.f + expf(-Sz));
    const float nn = tanhf(gin + bih[2*H_ + i] + rr * (ghn + bhh[2*H_ + i]));
    const float hp = hprev[(size_t)b * H_ + i];
    hnew[(size_t)b * H_ + i] = (1.f - zz) * nn + zz * hp;
}

// Logits phase body (r12 logits_kernel, blockIdx -> blk). blk in [0,250).
__device__ __forceinline__ void logits_phase(
    int blk, int tid, float* lds,
    const float* h1, const float* Wout, const float* bout,
    float* out_t, u64* tokpk_t)
{
    const int v0 = blk * 64;
    const int k4s = tid & 15;
    const int rr  = tid >> 4;

    const float *wq0, *wq1, *wq2, *wq3;
    int dW0, dW1, dW2, dW3;
    {
        const int r0 = rr, r1 = 16 + rr, r2 = 32 + rr, r3 = 48 + rr;
        wq0 = Wout + (size_t)(v0 + r0) * H_ + k4s * 4;
        wq1 = Wout + (size_t)(v0 + r1) * H_ + k4s * 4;
        wq2 = Wout + (size_t)(v0 + r2) * H_ + k4s * 4;
        wq3 = Wout + (size_t)(v0 + r3) * H_ + k4s * 4;
        dW0 = (r0 << 6) + ((k4s ^ (r0 & 7)) << 2);
        dW1 = (r1 << 6) + ((k4s ^ (r1 & 7)) << 2);
        dW2 = (r2 << 6) + ((k4s ^ (r2 & 7)) << 2);
        dW3 = (r3 << 6) + ((k4s ^ (r3 & 7)) << 2);
    }
    const float* aq0 = h1 + (size_t)rr * H_ + k4s * 4;
    const float* aq1 = h1 + (size_t)(rr + 16) * H_ + k4s * 4;
    const int dA0 = 4096 + (rr << 6) + ((k4s ^ (rr & 7)) << 2);
    const int dA1 = 4096 + ((rr + 16) << 6) + ((k4s ^ (rr & 7)) << 2);

    float acc[8][8] = {};
    gemm_core64(wq0, wq1, wq2, wq3, aq0, aq1,
                dW0, dW1, dW2, dW3, dA0, dA1, H_ >> 6, lds, tid, acc);
    reduce_totl(lds, tid, acc);

    u64* am = (u64*)(lds + 2176);            // [32][8], after totl
    {
        const int b = tid >> 3, seg = tid & 7;
        f32x4 x0 = *(f32x4*)&lds[b * 68 + seg * 8];
        f32x4 x1 = *(f32x4*)&lds[b * 68 + seg * 8 + 4];
        f32x4 bo0 = *(const f32x4*)(bout + v0 + seg * 8);
        f32x4 bo1 = *(const f32x4*)(bout + v0 + seg * 8 + 4);
        x0 += bo0; x1 += bo1;
        __builtin_nontemporal_store(
            x0, (f32x4*)(out_t + (size_t)b * V_ + v0 + seg * 8));
        __builtin_nontemporal_store(
            x1, (f32x4*)(out_t + (size_t)b * V_ + v0 + seg * 8 + 4));
        const int vb = v0 + seg * 8;
        float vals[8] = {x0.x, x0.y, x0.z, x0.w, x1.x, x1.y, x1.z, x1.w};
        u64 best = 0ull;
        #pragma unroll
        for (int i = 0; i < 8; i++) {
            u64 p = ((u64)fkey(vals[i]) << 32)
                  | (u64)(0xFFFFFFFFu - (unsigned)(vb + i));
            best = p > best ? p : best;
        }
        am[b * 8 + seg] = best;
    }
    __syncthreads();
    if (tid < 32) {
        u64 best = 0ull;
        #pragma unroll
        for (int q = 0; q < 8; q++) {
            u64 p = am[tid * 8 + q];
            best = p > best ? p : best;
        }
        atomicMax(&tokpk_t[(size_t)tid * TPAD_], best);
    }
}

// ---------------------------------------------------------------------------
// Persistent decoder: the whole T=64 decode in one kernel. Grid = 256 blocks
// (1/CU, residency forced by 82KB LDS), 5 grid barriers per step.
// ---------------------------------------------------------------------------
__global__ __launch_bounds__(256) void decoder_kernel(
    const float* __restrict__ embed,
    const float* __restrict__ Wih0, const float* __restrict__ Whh0,
    const float* __restrict__ bih0, const float* __restrict__ bhh0,
    const float* __restrict__ Wih1, const float* __restrict__ Whh1,
    const float* __restrict__ bih1, const float* __restrict__ bhh1,
    const float* __restrict__ Wout, const float* __restrict__ bout,
    float* __restrict__ out,
    float* __restrict__ h0buf, float* __restrict__ h1buf,
    float* __restrict__ gbuf, u64* __restrict__ tokpk,
    unsigned* __restrict__ bar)
{
    __shared__ float lds[20608];   // 82,432 B > 160KB/2: forces 1 block/CU
    const int blk = blockIdx.x;
    const int tid = threadIdx.x;
    const int BH = B_ * H_;

    for (int t = 0; t < T_; t++) {
        const int rp = t & 1, wp2 = (t + 1) & 1;
        const u64* tokprev = tokpk + (size_t)(t > 0 ? t - 1 : 0) * B_ * TPAD_;

        if (blk < 192)
            gru_gemm_phase(blk, tid, lds, Wih0, Whh0, E_, nullptr, 0,
                           embed, tokprev, t, /*tmode=*/1,
                           h0buf + (size_t)rp * BH, gbuf);
        gbar(bar, bar + 1);

        combine_phase(blk, tid, gbuf, bih0, bhh0,
                      h0buf + (size_t)rp * BH, h0buf + (size_t)wp2 * BH);
        gbar(bar, bar + 1);

        if (blk < 192)
            gru_gemm_phase(blk, tid, lds, Wih1, Whh1, H_,
                           h0buf + (size_t)wp2 * BH, H_,
                           embed, tokprev, 0, /*tmode=*/0,
                           h1buf + (size_t)rp * BH, gbuf);
        gbar(bar, bar + 1);

        combine_phase(blk, tid, gbuf, bih1, bhh1,
                      h1buf + (size_t)rp * BH, h1buf + (size_t)wp2 * BH);
        gbar(bar, bar + 1);

        if (blk < 250)
            logits_phase(blk, tid, lds, h1buf + (size_t)wp2 * BH, Wout, bout,
                         out + (size_t)t * B_ * V_,
                         tokpk + (size_t)t * B_ * TPAD_);
        gbar(bar, bar + 1);
    }
}

extern "C" void kernel_launch(void* const* d_in, const int* in_sizes, int n_in,
                              void* d_out, int out_size, void* d_ws, size_t ws_size,
                              hipStream_t stream) {
    const float* hidden = (const float*)d_in[0];
    const float* embed  = (const float*)d_in[1];
    const float* Wih0   = (const float*)d_in[2];
    const float* Whh0   = (const float*)d_in[3];
    const float* bih0   = (const float*)d_in[4];
    const float* bhh0   = (const float*)d_in[5];
    const float* Wih1   = (const float*)d_in[6];
    const float* Whh1   = (const float*)d_in[7];
    const float* bih1   = (const float*)d_in[8];
    const float* bhh1   = (const float*)d_in[9];
    const float* Wout   = (const float*)d_in[10];
    const float* bout   = (const float*)d_in[11];
    float* out = (float*)d_out;

    const int BH = B_ * H_;
    float* ws = (float*)d_ws;
    float* h0buf = ws;                        // [2][B][H]
    float* h1buf = ws + 2 * BH;               // [2][B][H]
    float* gbuf  = ws + 4 * BH;               // [2][B][NR_]
    u64* tokpk = (u64*)(ws + 4 * BH + 2 * B_ * NR_);  // [T][B*TPAD_]
    unsigned* bar = (unsigned*)(tokpk + (size_t)T_ * B_ * TPAD_);  // [2]

    init_kernel<<<128, 256, 0, stream>>>(hidden, h0buf, h1buf, tokpk, bar);

    decoder_kernel<<<NBLK_, 256, 0, stream>>>(
        embed, Wih0, Whh0, bih0, bhh0, Wih1, Whh1, bih1, bhh1,
        Wout, bout, out, h0buf, h1buf, gbuf, tokpk, bar);
}

// Round 14
// 5449.194 us; speedup vs baseline: 3.0270x; 3.0270x over previous
//
#include <hip/hip_runtime.h>
#include <stdint.h>

#define V_ 16000
#define E_ 512
#define H_ 1024
#define B_ 32
#define T_ 64
#define NG_ 3072        // 3*H rows per weight matrix
#define NR_ 6144        // virtual rows in gru gemm (ih + hh)
#define TPAD_ 8         // u64 stride per batch token slot
#define NBLK_ 256       // persistent grid = #CUs

typedef float f32x4 __attribute__((ext_vector_type(4)));
typedef unsigned long long u64;

__device__ __forceinline__ unsigned int fkey(float f) {
    unsigned int u = __float_as_uint(f);
    return (u & 0x80000000u) ? ~u : (u | 0x80000000u);
}

// ---- device-coherent (agent-scope, sc1) access helpers -------------------
// Relaxed agent atomics are routed to the coherence point (bypass the
// non-coherent per-XCD L2s) -> cross-block data needs NO fences anywhere.
__device__ __forceinline__ f32x4 ld_cohx4(const float* p) {
    u64 lo = __hip_atomic_load((const u64*)p,       __ATOMIC_RELAXED,
                               __HIP_MEMORY_SCOPE_AGENT);
    u64 hi = __hip_atomic_load(((const u64*)p) + 1, __ATOMIC_RELAXED,
                               __HIP_MEMORY_SCOPE_AGENT);
    union { u64 q[2]; f32x4 v; } u;
    u.q[0] = lo; u.q[1] = hi;
    return u.v;
}
__device__ __forceinline__ void st_cohx4(float* p, f32x4 v) {
    union { u64 q[2]; f32x4 v; } u;
    u.v = v;
    __hip_atomic_store((u64*)p,       u.q[0], __ATOMIC_RELAXED,
                       __HIP_MEMORY_SCOPE_AGENT);
    __hip_atomic_store(((u64*)p) + 1, u.q[1], __ATOMIC_RELAXED,
                       __HIP_MEMORY_SCOPE_AGENT);
}
__device__ __forceinline__ float ld_cohf(const float* p) {
    return __hip_atomic_load(p, __ATOMIC_RELAXED, __HIP_MEMORY_SCOPE_AGENT);
}
__device__ __forceinline__ void st_cohf(float* p, float v) {
    __hip_atomic_store(p, v, __ATOMIC_RELAXED, __HIP_MEMORY_SCOPE_AGENT);
}
__device__ __forceinline__ u64 ld_cohu64(const u64* p) {
    return __hip_atomic_load(p, __ATOMIC_RELAXED, __HIP_MEMORY_SCOPE_AGENT);
}

// Monotonic fence-free grid barrier. k = 1,2,3,... per call site sequence.
// cnt at bar[0], gen at bar[16] (separate 64B lines). No reset -> no race.
// The single leader's RELEASE orders nothing heavy (one wb total/barrier).
__device__ __forceinline__ void gbar(unsigned* cnt, unsigned* gen, unsigned k) {
    __syncthreads();   // drains vmcnt: all block stores at coherence point
    if (threadIdx.x == 0) {
        unsigned a = __hip_atomic_fetch_add(cnt, 1u, __ATOMIC_RELAXED,
                                            __HIP_MEMORY_SCOPE_AGENT);
        if (a == k * NBLK_ - 1u) {
            __hip_atomic_fetch_add(gen, 1u, __ATOMIC_RELEASE,
                                   __HIP_MEMORY_SCOPE_AGENT);
        } else {
            while (__hip_atomic_load(gen, __ATOMIC_RELAXED,
                                     __HIP_MEMORY_SCOPE_AGENT) < k)
                __builtin_amdgcn_s_sleep(2);
        }
    }
    __syncthreads();
}

__global__ void init_kernel(const float* __restrict__ hidden,
                            float* __restrict__ h0, float* __restrict__ h1,
                            u64* __restrict__ tokpk, unsigned* __restrict__ bar) {
    int idx = blockIdx.x * blockDim.x + threadIdx.x;
    if (idx < B_ * H_) {
        h0[idx] = hidden[idx];
        h1[idx] = hidden[B_ * H_ + idx];
    }
    if (idx < T_ * B_ * TPAD_) tokpk[idx] = 0ull;
    if (idx < 32) bar[idx] = 0u;
}

// ---------------------------------------------------------------------------
// r12-proven 64-row x 32-batch streamed GEMM core, 256 threads, acc[8][8].
// CA: A-operand loaded device-coherent (h-buffers) vs plain (embed/Wout...).
// ---------------------------------------------------------------------------
template<bool CA>
__device__ __forceinline__ void gemm_core64(
    const float* wq0, const float* wq1, const float* wq2, const float* wq3,
    const float* aq0, const float* aq1,
    int dW0, int dW1, int dW2, int dW3, int dA0, int dA1,
    int nch, float* lds, int tid, float acc[8][8])
{
    const int ks = tid >> 5, pos = tid & 31;
    const int rg = pos >> 2, bgp = pos & 3;

    f32x4 w0 = *(const f32x4*)wq0, w1 = *(const f32x4*)wq1;
    f32x4 w2 = *(const f32x4*)wq2, w3 = *(const f32x4*)wq3;
    f32x4 a0 = CA ? ld_cohx4(aq0) : *(const f32x4*)aq0;
    f32x4 a1 = CA ? ld_cohx4(aq1) : *(const f32x4*)aq1;
    *(f32x4*)&lds[dW0] = w0; *(f32x4*)&lds[dW1] = w1;
    *(f32x4*)&lds[dW2] = w2; *(f32x4*)&lds[dW3] = w3;
    *(f32x4*)&lds[dA0] = a0; *(f32x4*)&lds[dA1] = a1;
    __syncthreads();

    int cur = 0;
    for (int c = 0; c < nch; c++) {
        if (c + 1 < nch) {
            const int o = (c + 1) << 6;
            w0 = *(const f32x4*)(wq0 + o); w1 = *(const f32x4*)(wq1 + o);
            w2 = *(const f32x4*)(wq2 + o); w3 = *(const f32x4*)(wq3 + o);
            a0 = CA ? ld_cohx4(aq0 + o) : *(const f32x4*)(aq0 + o);
            a1 = CA ? ld_cohx4(aq1 + o) : *(const f32x4*)(aq1 + o);
        }
        const float* Wb = &lds[cur * 6144];
        const float* Ab = Wb + 4096;
        #pragma unroll
        for (int kk = 0; kk < 2; kk++) {
            const int k4 = ks * 2 + kk;
            f32x4 ww[8], ha[8];
            #pragma unroll
            for (int vi = 0; vi < 8; vi++) {
                const int row = rg + 8 * vi;           // row&7 == rg
                ww[vi] = *(const f32x4*)&Wb[(row << 6) + ((k4 ^ rg) << 2)];
            }
            #pragma unroll
            for (int j = 0; j < 8; j++) {
                const int br = bgp + 4 * j;
                ha[j] = *(const f32x4*)&Ab[(br << 6) + ((k4 ^ (br & 7)) << 2)];
            }
            #pragma unroll
            for (int vi = 0; vi < 8; vi++)
                #pragma unroll
                for (int j = 0; j < 8; j++)
                    acc[vi][j] += ww[vi].x*ha[j].x + ww[vi].y*ha[j].y
                                + ww[vi].z*ha[j].z + ww[vi].w*ha[j].w;
        }
        if (c + 1 < nch) {
            float* L = &lds[(cur ^ 1) * 6144];
            *(f32x4*)&L[dW0] = w0; *(f32x4*)&L[dW1] = w1;
            *(f32x4*)&L[dW2] = w2; *(f32x4*)&L[dW3] = w3;
            *(f32x4*)&L[dA0] = a0; *(f32x4*)&L[dA1] = a1;
        }
        __syncthreads();
        cur ^= 1;
    }
}

__device__ __forceinline__ void reduce_totl(float* lds, int tid, float acc[8][8])
{
    const int ks = tid >> 5, pos = tid & 31;
    {
        float* dst = &lds[(ks * 32 + pos) * 68];
        #pragma unroll
        for (int vi = 0; vi < 8; vi++) {
            f32x4 p0 = {acc[vi][0], acc[vi][1], acc[vi][2], acc[vi][3]};
            f32x4 p1 = {acc[vi][4], acc[vi][5], acc[vi][6], acc[vi][7]};
            *(f32x4*)&dst[vi * 8]     = p0;
            *(f32x4*)&dst[vi * 8 + 4] = p1;
        }
    }
    __syncthreads();
    const int vi2 = tid >> 5, pos2 = tid & 31;
    f32x4 s0 = {0.f, 0.f, 0.f, 0.f}, s1 = {0.f, 0.f, 0.f, 0.f};
    #pragma unroll
    for (int k = 0; k < 8; k++) {
        const float* src = &lds[(k * 32 + pos2) * 68 + vi2 * 8];
        s0 += *(const f32x4*)src;
        s1 += *(const f32x4*)(src + 4);
    }
    __syncthreads();
    const int row = (pos2 >> 2) + 8 * vi2;   // 0..63
    const int bb  = pos2 & 3;                // batch = bb + 4*j
    lds[(bb +  0) * 68 + row] = s0.x;
    lds[(bb +  4) * 68 + row] = s0.y;
    lds[(bb +  8) * 68 + row] = s0.z;
    lds[(bb + 12) * 68 + row] = s0.w;
    lds[(bb + 16) * 68 + row] = s1.x;
    lds[(bb + 20) * 68 + row] = s1.y;
    lds[(bb + 24) * 68 + row] = s1.z;
    lds[(bb + 28) * 68 + row] = s1.w;
    __syncthreads();
}

// GRU GEMM phase body (r12-verbatim math). blk in [0,192).
__device__ __forceinline__ void gru_gemm_phase(
    int blk0, int tid, float* lds,
    const float* Wih, const float* Whh, int Kih,
    const float* xbase, int xld,
    const float* embed, const u64* tokprev, int t, int tmode,
    const float* hprev, float* gbuf)
{
    const int kslice = blk0 >= 96 ? 1 : 0;
    const int tile = blk0 - kslice * 96;
    const int k4s = tid & 15;
    const int rr  = tid >> 4;                // 0..15

    const float* Wbase; int K, n0, nout;
    const float *ar0, *ar1;
    bool cohA;
    if (tile < 48) {
        n0 = tile * 64; nout = n0; Wbase = Wih; K = Kih;
        if (tmode) {
            int tok0 = 0, tok1 = 0;
            if (t > 0) {
                tok0 = (int)(0xFFFFFFFFu -
                       (unsigned)(ld_cohu64(&tokprev[(size_t)rr * TPAD_]) & 0xFFFFFFFFull));
                tok1 = (int)(0xFFFFFFFFu -
                       (unsigned)(ld_cohu64(&tokprev[(size_t)(rr + 16) * TPAD_]) & 0xFFFFFFFFull));
            }
            ar0 = embed + (size_t)tok0 * Kih;
            ar1 = embed + (size_t)tok1 * Kih;
            cohA = false;                    // embed is read-only
        } else {
            ar0 = xbase + (size_t)rr * xld;
            ar1 = xbase + (size_t)(rr + 16) * xld;
            cohA = true;                     // h0' written by other blocks
        }
    } else {
        n0 = (tile - 48) * 64; nout = NG_ + n0; Wbase = Whh; K = H_;
        ar0 = hprev + (size_t)rr * H_;
        ar1 = hprev + (size_t)(rr + 16) * H_;
        cohA = true;
    }
    const int koff = kslice * (K >> 1);
    const int nch  = K >> 7;                 // 4 or 8 chunks

    const float *wq0, *wq1, *wq2, *wq3;
    int dW0, dW1, dW2, dW3;
    {
        const int r0 = rr, r1 = 16 + rr, r2 = 32 + rr, r3 = 48 + rr;
        wq0 = Wbase + (size_t)(n0 + r0) * K + koff + k4s * 4;
        wq1 = Wbase + (size_t)(n0 + r1) * K + koff + k4s * 4;
        wq2 = Wbase + (size_t)(n0 + r2) * K + koff + k4s * 4;
        wq3 = Wbase + (size_t)(n0 + r3) * K + koff + k4s * 4;
        dW0 = (r0 << 6) + ((k4s ^ (r0 & 7)) << 2);
        dW1 = (r1 << 6) + ((k4s ^ (r1 & 7)) << 2);
        dW2 = (r2 << 6) + ((k4s ^ (r2 & 7)) << 2);
        dW3 = (r3 << 6) + ((k4s ^ (r3 & 7)) << 2);
    }
    const float* aq0 = ar0 + koff + k4s * 4;
    const float* aq1 = ar1 + koff + k4s * 4;
    const int dA0 = 4096 + (rr << 6) + ((k4s ^ (rr & 7)) << 2);
    const int dA1 = 4096 + ((rr + 16) << 6) + ((k4s ^ (rr & 7)) << 2);

    float acc[8][8] = {};
    if (cohA)
        gemm_core64<true>(wq0, wq1, wq2, wq3, aq0, aq1,
                          dW0, dW1, dW2, dW3, dA0, dA1, nch, lds, tid, acc);
    else
        gemm_core64<false>(wq0, wq1, wq2, wq3, aq0, aq1,
                           dW0, dW1, dW2, dW3, dA0, dA1, nch, lds, tid, acc);
    reduce_totl(lds, tid, acc);

    {
        const int b = tid >> 3, seg = tid & 7;
        float* gout = gbuf + (size_t)kslice * B_ * NR_
                    + (size_t)b * NR_ + nout + seg * 8;
        f32x4 x0 = *(f32x4*)&lds[b * 68 + seg * 8];
        f32x4 x1 = *(f32x4*)&lds[b * 68 + seg * 8 + 4];
        st_cohx4(gout, x0);
        st_cohx4(gout + 4, x1);
    }
}

// Combine phase: 32768 elems over 256 blocks x 128 active threads.
__device__ __forceinline__ void combine_phase(
    int blk, int tid, const float* gbuf,
    const float* bih, const float* bhh,
    const float* hprev, float* hnew)
{
    if (tid >= 128) return;
    const int idx = blk * 128 + tid;          // 0..32767
    const int b = idx >> 10, i = idx & 1023;
    const float* gb0 = gbuf + (size_t)b * NR_;
    const float* gb1 = gbuf + (size_t)(B_ + b) * NR_;
    const float gir = ld_cohf(gb0 + i)              + ld_cohf(gb1 + i);
    const float giz = ld_cohf(gb0 + H_ + i)         + ld_cohf(gb1 + H_ + i);
    const float gin = ld_cohf(gb0 + 2*H_ + i)       + ld_cohf(gb1 + 2*H_ + i);
    const float ghr = ld_cohf(gb0 + NG_ + i)        + ld_cohf(gb1 + NG_ + i);
    const float ghz = ld_cohf(gb0 + NG_ + H_ + i)   + ld_cohf(gb1 + NG_ + H_ + i);
    const float ghn = ld_cohf(gb0 + NG_ + 2*H_ + i) + ld_cohf(gb1 + NG_ + 2*H_ + i);
    const float Sr = gir + ghr + bih[i] + bhh[i];
    const float Sz = giz + ghz + bih[H_ + i] + bhh[H_ + i];
    const float rr = 1.f / (1.f + expf(-Sr));
    const float zz = 1.f / (1.f + expf(-Sz));
    const float nn = tanhf(gin + bih[2*H_ + i] + rr * (ghn + bhh[2*H_ + i]));
    const float hp = ld_cohf(hprev + (size_t)b * H_ + i);
    st_cohf(hnew + (size_t)b * H_ + i, (1.f - zz) * nn + zz * hp);
}

// Logits phase body (r12-verbatim math). blk in [0,250).
__device__ __forceinline__ void logits_phase(
    int blk, int tid, float* lds,
    const float* h1, const float* Wout, const float* bout,
    float* out_t, u64* tokpk_t)
{
    const int v0 = blk * 64;
    const int k4s = tid & 15;
    const int rr  = tid >> 4;

    const float *wq0, *wq1, *wq2, *wq3;
    int dW0, dW1, dW2, dW3;
    {
        const int r0 = rr, r1 = 16 + rr, r2 = 32 + rr, r3 = 48 + rr;
        wq0 = Wout + (size_t)(v0 + r0) * H_ + k4s * 4;
        wq1 = Wout + (size_t)(v0 + r1) * H_ + k4s * 4;
        wq2 = Wout + (size_t)(v0 + r2) * H_ + k4s * 4;
        wq3 = Wout + (size_t)(v0 + r3) * H_ + k4s * 4;
        dW0 = (r0 << 6) + ((k4s ^ (r0 & 7)) << 2);
        dW1 = (r1 << 6) + ((k4s ^ (r1 & 7)) << 2);
        dW2 = (r2 << 6) + ((k4s ^ (r2 & 7)) << 2);
        dW3 = (r3 << 6) + ((k4s ^ (r3 & 7)) << 2);
    }
    const float* aq0 = h1 + (size_t)rr * H_ + k4s * 4;
    const float* aq1 = h1 + (size_t)(rr + 16) * H_ + k4s * 4;
    const int dA0 = 4096 + (rr << 6) + ((k4s ^ (rr & 7)) << 2);
    const int dA1 = 4096 + ((rr + 16) << 6) + ((k4s ^ (rr & 7)) << 2);

    float acc[8][8] = {};
    gemm_core64<true>(wq0, wq1, wq2, wq3, aq0, aq1,
                      dW0, dW1, dW2, dW3, dA0, dA1, H_ >> 6, lds, tid, acc);
    reduce_totl(lds, tid, acc);

    u64* am = (u64*)(lds + 2176);            // [32][8], after totl
    {
        const int b = tid >> 3, seg = tid & 7;
        f32x4 x0 = *(f32x4*)&lds[b * 68 + seg * 8];
        f32x4 x1 = *(f32x4*)&lds[b * 68 + seg * 8 + 4];
        f32x4 bo0 = *(const f32x4*)(bout + v0 + seg * 8);
        f32x4 bo1 = *(const f32x4*)(bout + v0 + seg * 8 + 4);
        x0 += bo0; x1 += bo1;
        __builtin_nontemporal_store(
            x0, (f32x4*)(out_t + (size_t)b * V_ + v0 + seg * 8));
        __builtin_nontemporal_store(
            x1, (f32x4*)(out_t + (size_t)b * V_ + v0 + seg * 8 + 4));
        const int vb = v0 + seg * 8;
        float vals[8] = {x0.x, x0.y, x0.z, x0.w, x1.x, x1.y, x1.z, x1.w};
        u64 best = 0ull;
        #pragma unroll
        for (int i = 0; i < 8; i++) {
            u64 p = ((u64)fkey(vals[i]) << 32)
                  | (u64)(0xFFFFFFFFu - (unsigned)(vb + i));
            best = p > best ? p : best;
        }
        am[b * 8 + seg] = best;
    }
    __syncthreads();
    if (tid < 32) {
        u64 best = 0ull;
        #pragma unroll
        for (int q = 0; q < 8; q++) {
            u64 p = am[tid * 8 + q];
            best = p > best ? p : best;
        }
        atomicMax(&tokpk_t[(size_t)tid * TPAD_], best);
    }
}

// ---------------------------------------------------------------------------
// Persistent decoder: whole T=64 decode in one kernel. Grid = 256 blocks
// (1/CU forced by 82KB LDS), 5 fence-free grid barriers per step.
// ---------------------------------------------------------------------------
__global__ __launch_bounds__(256) void decoder_kernel(
    const float* __restrict__ embed,
    const float* __restrict__ Wih0, const float* __restrict__ Whh0,
    const float* __restrict__ bih0, const float* __restrict__ bhh0,
    const float* __restrict__ Wih1, const float* __restrict__ Whh1,
    const float* __restrict__ bih1, const float* __restrict__ bhh1,
    const float* __restrict__ Wout, const float* __restrict__ bout,
    float* __restrict__ out,
    float* __restrict__ h0buf, float* __restrict__ h1buf,
    float* __restrict__ gbuf, u64* __restrict__ tokpk,
    unsigned* __restrict__ bar)
{
    __shared__ float lds[20608];   // 82,432 B > 160KB/2: forces 1 block/CU
    const int blk = blockIdx.x;
    const int tid = threadIdx.x;
    const int BH = B_ * H_;
    unsigned* cnt = bar;
    unsigned* gen = bar + 16;      // separate 64B cache line
    unsigned bk = 0;

    for (int t = 0; t < T_; t++) {
        const int rp = t & 1, wp2 = (t + 1) & 1;
        const u64* tokprev = tokpk + (size_t)(t > 0 ? t - 1 : 0) * B_ * TPAD_;

        if (blk < 192)
            gru_gemm_phase(blk, tid, lds, Wih0, Whh0, E_, nullptr, 0,
                           embed, tokprev, t, /*tmode=*/1,
                           h0buf + (size_t)rp * BH, gbuf);
        gbar(cnt, gen, ++bk);

        combine_phase(blk, tid, gbuf, bih0, bhh0,
                      h0buf + (size_t)rp * BH, h0buf + (size_t)wp2 * BH);
        gbar(cnt, gen, ++bk);

        if (blk < 192)
            gru_gemm_phase(blk, tid, lds, Wih1, Whh1, H_,
                           h0buf + (size_t)wp2 * BH, H_,
                           embed, tokprev, 0, /*tmode=*/0,
                           h1buf + (size_t)rp * BH, gbuf);
        gbar(cnt, gen, ++bk);

        combine_phase(blk, tid, gbuf, bih1, bhh1,
                      h1buf + (size_t)rp * BH, h1buf + (size_t)wp2 * BH);
        gbar(cnt, gen, ++bk);

        if (blk < 250)
            logits_phase(blk, tid, lds, h1buf + (size_t)wp2 * BH, Wout, bout,
                         out + (size_t)t * B_ * V_,
                         tokpk + (size_t)t * B_ * TPAD_);
        gbar(cnt, gen, ++bk);
    }
}

extern "C" void kernel_launch(void* const* d_in, const int* in_sizes, int n_in,
                              void* d_out, int out_size, void* d_ws, size_t ws_size,
                              hipStream_t stream) {
    const float* hidden = (const float*)d_in[0];
    const float* embed  = (const float*)d_in[1];
    const float* Wih0   = (const float*)d_in[2];
    const float* Whh0   = (const float*)d_in[3];
    const float* bih0   = (const float*)d_in[4];
    const float* bhh0   = (const float*)d_in[5];
    const float* Wih1   = (const float*)d_in[6];
    const float* Whh1   = (const float*)d_in[7];
    const float* bih1   = (const float*)d_in[8];
    const float* bhh1   = (const float*)d_in[9];
    const float* Wout   = (const float*)d_in[10];
    const float* bout   = (const float*)d_in[11];
    float* out = (float*)d_out;

    const int BH = B_ * H_;
    float* ws = (float*)d_ws;
    float* h0buf = ws;                        // [2][B][H]
    float* h1buf = ws + 2 * BH;               // [2][B][H]
    float* gbuf  = ws + 4 * BH;               // [2][B][NR_]
    u64* tokpk = (u64*)(ws + 4 * BH + 2 * B_ * NR_);  // [T][B*TPAD_]
    unsigned* bar = (unsigned*)(tokpk + (size_t)T_ * B_ * TPAD_);  // [32]

    init_kernel<<<128, 256, 0, stream>>>(hidden, h0buf, h1buf, tokpk, bar);

    decoder_kernel<<<NBLK_, 256, 0, stream>>>(
        embed, Wih0, Whh0, bih0, bhh0, Wih1, Whh1, bih1, bhh1,
        Wout, bout, out, h0buf, h1buf, gbuf, tokpk, bar);
}

// Round 15
// 4198.318 us; speedup vs baseline: 3.9289x; 1.2979x over previous
//
#include <hip/hip_runtime.h>
#include <stdint.h>

#define V_ 16000
#define E_ 512
#define H_ 1024
#define B_ 32
#define T_ 64
#define NG_ 3072        // 3*H rows per weight matrix
#define NR_ 6144        // virtual rows in gru gemm (ih + hh)
#define TPAD_ 8         // u64 stride per batch token slot
#define NBLK_ 256       // persistent grid = #CUs

typedef float f32x4 __attribute__((ext_vector_type(4)));
typedef unsigned long long u64;

__device__ __forceinline__ unsigned int fkey(float f) {
    unsigned int u = __float_as_uint(f);
    return (u & 0x80000000u) ? ~u : (u | 0x80000000u);
}

// ---- device-coherent (agent-scope, sc1) access helpers -------------------
__device__ __forceinline__ f32x4 ld_cohx4(const float* p) {
    u64 lo = __hip_atomic_load((const u64*)p,       __ATOMIC_RELAXED,
                               __HIP_MEMORY_SCOPE_AGENT);
    u64 hi = __hip_atomic_load(((const u64*)p) + 1, __ATOMIC_RELAXED,
                               __HIP_MEMORY_SCOPE_AGENT);
    union { u64 q[2]; f32x4 v; } u;
    u.q[0] = lo; u.q[1] = hi;
    return u.v;
}
__device__ __forceinline__ void st_cohx4(float* p, f32x4 v) {
    union { u64 q[2]; f32x4 v; } u;
    u.v = v;
    __hip_atomic_store((u64*)p,       u.q[0], __ATOMIC_RELAXED,
                       __HIP_MEMORY_SCOPE_AGENT);
    __hip_atomic_store(((u64*)p) + 1, u.q[1], __ATOMIC_RELAXED,
                       __HIP_MEMORY_SCOPE_AGENT);
}
__device__ __forceinline__ float ld_cohf(const float* p) {
    return __hip_atomic_load(p, __ATOMIC_RELAXED, __HIP_MEMORY_SCOPE_AGENT);
}
__device__ __forceinline__ void st_cohf(float* p, float v) {
    __hip_atomic_store(p, v, __ATOMIC_RELAXED, __HIP_MEMORY_SCOPE_AGENT);
}
__device__ __forceinline__ u64 ld_cohu64(const u64* p) {
    return __hip_atomic_load(p, __ATOMIC_RELAXED, __HIP_MEMORY_SCOPE_AGENT);
}

// Hierarchical monotonic fence-free grid barrier (two-level 16x16).
// bar layout (u32): l0 counters at [g*16], g=0..15 (64B-strided lines);
// root at [256]; gen at [272]. k = 1,2,3,... per call-site sequence.
// Arrival: <=16 serialized RMWs per l0 line (parallel across groups) +
// <=16 on root -> worst serial chain ~32 RMWs (~1.6us) vs 256 (~13us, r14).
__device__ __forceinline__ void gbar(unsigned* bar, unsigned k) {
    __syncthreads();   // drains vmcnt: block's coherent stores are visible
    if (threadIdx.x == 0) {
        unsigned* gen = bar + 272;
        unsigned* l0  = bar + ((blockIdx.x & 15u) << 4);
        bool last = false;
        unsigned a = __hip_atomic_fetch_add(l0, 1u, __ATOMIC_RELAXED,
                                            __HIP_MEMORY_SCOPE_AGENT);
        if (a == k * 16u - 1u) {   // last of my 16-block group
            unsigned r = __hip_atomic_fetch_add(bar + 256, 1u, __ATOMIC_RELAXED,
                                                __HIP_MEMORY_SCOPE_AGENT);
            if (r == k * 16u - 1u) {  // last group
                __hip_atomic_fetch_add(gen, 1u, __ATOMIC_RELEASE,
                                       __HIP_MEMORY_SCOPE_AGENT);
                last = true;
            }
        }
        if (!last) {
            while (__hip_atomic_load(gen, __ATOMIC_RELAXED,
                                     __HIP_MEMORY_SCOPE_AGENT) < k)
                __builtin_amdgcn_s_sleep(1);
        }
    }
    __syncthreads();
}

__global__ void init_kernel(const float* __restrict__ hidden,
                            float* __restrict__ h0, float* __restrict__ h1,
                            u64* __restrict__ tokpk, unsigned* __restrict__ bar) {
    int idx = blockIdx.x * blockDim.x + threadIdx.x;
    if (idx < B_ * H_) {
        h0[idx] = hidden[idx];
        h1[idx] = hidden[B_ * H_ + idx];
    }
    if (idx < T_ * B_ * TPAD_) tokpk[idx] = 0ull;
    if (idx < 288) bar[idx] = 0u;
}

// ---------------------------------------------------------------------------
// r12-proven 64-row x 32-batch streamed GEMM core, 256 threads, acc[8][8].
// CA: A-operand loaded device-coherent (h-buffers) vs plain (embed/Wout...).
// ---------------------------------------------------------------------------
template<bool CA>
__device__ __forceinline__ void gemm_core64(
    const float* wq0, const float* wq1, const float* wq2, const float* wq3,
    const float* aq0, const float* aq1,
    int dW0, int dW1, int dW2, int dW3, int dA0, int dA1,
    int nch, float* lds, int tid, float acc[8][8])
{
    const int ks = tid >> 5, pos = tid & 31;
    const int rg = pos >> 2, bgp = pos & 3;

    f32x4 w0 = *(const f32x4*)wq0, w1 = *(const f32x4*)wq1;
    f32x4 w2 = *(const f32x4*)wq2, w3 = *(const f32x4*)wq3;
    f32x4 a0 = CA ? ld_cohx4(aq0) : *(const f32x4*)aq0;
    f32x4 a1 = CA ? ld_cohx4(aq1) : *(const f32x4*)aq1;
    *(f32x4*)&lds[dW0] = w0; *(f32x4*)&lds[dW1] = w1;
    *(f32x4*)&lds[dW2] = w2; *(f32x4*)&lds[dW3] = w3;
    *(f32x4*)&lds[dA0] = a0; *(f32x4*)&lds[dA1] = a1;
    __syncthreads();

    int cur = 0;
    for (int c = 0; c < nch; c++) {
        if (c + 1 < nch) {
            const int o = (c + 1) << 6;
            w0 = *(const f32x4*)(wq0 + o); w1 = *(const f32x4*)(wq1 + o);
            w2 = *(const f32x4*)(wq2 + o); w3 = *(const f32x4*)(wq3 + o);
            a0 = CA ? ld_cohx4(aq0 + o) : *(const f32x4*)(aq0 + o);
            a1 = CA ? ld_cohx4(aq1 + o) : *(const f32x4*)(aq1 + o);
        }
        const float* Wb = &lds[cur * 6144];
        const float* Ab = Wb + 4096;
        #pragma unroll
        for (int kk = 0; kk < 2; kk++) {
            const int k4 = ks * 2 + kk;
            f32x4 ww[8], ha[8];
            #pragma unroll
            for (int vi = 0; vi < 8; vi++) {
                const int row = rg + 8 * vi;           // row&7 == rg
                ww[vi] = *(const f32x4*)&Wb[(row << 6) + ((k4 ^ rg) << 2)];
            }
            #pragma unroll
            for (int j = 0; j < 8; j++) {
                const int br = bgp + 4 * j;
                ha[j] = *(const f32x4*)&Ab[(br << 6) + ((k4 ^ (br & 7)) << 2)];
            }
            #pragma unroll
            for (int vi = 0; vi < 8; vi++)
                #pragma unroll
                for (int j = 0; j < 8; j++)
                    acc[vi][j] += ww[vi].x*ha[j].x + ww[vi].y*ha[j].y
                                + ww[vi].z*ha[j].z + ww[vi].w*ha[j].w;
        }
        if (c + 1 < nch) {
            float* L = &lds[(cur ^ 1) * 6144];
            *(f32x4*)&L[dW0] = w0; *(f32x4*)&L[dW1] = w1;
            *(f32x4*)&L[dW2] = w2; *(f32x4*)&L[dW3] = w3;
            *(f32x4*)&L[dA0] = a0; *(f32x4*)&L[dA1] = a1;
        }
        __syncthreads();
        cur ^= 1;
    }
}

__device__ __forceinline__ void reduce_totl(float* lds, int tid, float acc[8][8])
{
    const int ks = tid >> 5, pos = tid & 31;
    {
        float* dst = &lds[(ks * 32 + pos) * 68];
        #pragma unroll
        for (int vi = 0; vi < 8; vi++) {
            f32x4 p0 = {acc[vi][0], acc[vi][1], acc[vi][2], acc[vi][3]};
            f32x4 p1 = {acc[vi][4], acc[vi][5], acc[vi][6], acc[vi][7]};
            *(f32x4*)&dst[vi * 8]     = p0;
            *(f32x4*)&dst[vi * 8 + 4] = p1;
        }
    }
    __syncthreads();
    const int vi2 = tid >> 5, pos2 = tid & 31;
    f32x4 s0 = {0.f, 0.f, 0.f, 0.f}, s1 = {0.f, 0.f, 0.f, 0.f};
    #pragma unroll
    for (int k = 0; k < 8; k++) {
        const float* src = &lds[(k * 32 + pos2) * 68 + vi2 * 8];
        s0 += *(const f32x4*)src;
        s1 += *(const f32x4*)(src + 4);
    }
    __syncthreads();
    const int row = (pos2 >> 2) + 8 * vi2;   // 0..63
    const int bb  = pos2 & 3;                // batch = bb + 4*j
    lds[(bb +  0) * 68 + row] = s0.x;
    lds[(bb +  4) * 68 + row] = s0.y;
    lds[(bb +  8) * 68 + row] = s0.z;
    lds[(bb + 12) * 68 + row] = s0.w;
    lds[(bb + 16) * 68 + row] = s1.x;
    lds[(bb + 20) * 68 + row] = s1.y;
    lds[(bb + 24) * 68 + row] = s1.z;
    lds[(bb + 28) * 68 + row] = s1.w;
    __syncthreads();
}

// GRU GEMM phase body (r12-verbatim math). blk in [0,192).
__device__ __forceinline__ void gru_gemm_phase(
    int blk0, int tid, float* lds,
    const float* Wih, const float* Whh, int Kih,
    const float* xbase, int xld,
    const float* embed, const u64* tokprev, int t, int tmode,
    const float* hprev, float* gbuf)
{
    const int kslice = blk0 >= 96 ? 1 : 0;
    const int tile = blk0 - kslice * 96;
    const int k4s = tid & 15;
    const int rr  = tid >> 4;                // 0..15

    const float* Wbase; int K, n0, nout;
    const float *ar0, *ar1;
    bool cohA;
    if (tile < 48) {
        n0 = tile * 64; nout = n0; Wbase = Wih; K = Kih;
        if (tmode) {
            int tok0 = 0, tok1 = 0;
            if (t > 0) {
                tok0 = (int)(0xFFFFFFFFu -
                       (unsigned)(ld_cohu64(&tokprev[(size_t)rr * TPAD_]) & 0xFFFFFFFFull));
                tok1 = (int)(0xFFFFFFFFu -
                       (unsigned)(ld_cohu64(&tokprev[(size_t)(rr + 16) * TPAD_]) & 0xFFFFFFFFull));
            }
            ar0 = embed + (size_t)tok0 * Kih;
            ar1 = embed + (size_t)tok1 * Kih;
            cohA = false;                    // embed is read-only
        } else {
            ar0 = xbase + (size_t)rr * xld;
            ar1 = xbase + (size_t)(rr + 16) * xld;
            cohA = true;                     // h0' written by other blocks
        }
    } else {
        n0 = (tile - 48) * 64; nout = NG_ + n0; Wbase = Whh; K = H_;
        ar0 = hprev + (size_t)rr * H_;
        ar1 = hprev + (size_t)(rr + 16) * H_;
        cohA = true;
    }
    const int koff = kslice * (K >> 1);
    const int nch  = K >> 7;                 // 4 or 8 chunks

    const float *wq0, *wq1, *wq2, *wq3;
    int dW0, dW1, dW2, dW3;
    {
        const int r0 = rr, r1 = 16 + rr, r2 = 32 + rr, r3 = 48 + rr;
        wq0 = Wbase + (size_t)(n0 + r0) * K + koff + k4s * 4;
        wq1 = Wbase + (size_t)(n0 + r1) * K + koff + k4s * 4;
        wq2 = Wbase + (size_t)(n0 + r2) * K + koff + k4s * 4;
        wq3 = Wbase + (size_t)(n0 + r3) * K + koff + k4s * 4;
        dW0 = (r0 << 6) + ((k4s ^ (r0 & 7)) << 2);
        dW1 = (r1 << 6) + ((k4s ^ (r1 & 7)) << 2);
        dW2 = (r2 << 6) + ((k4s ^ (r2 & 7)) << 2);
        dW3 = (r3 << 6) + ((k4s ^ (r3 & 7)) << 2);
    }
    const float* aq0 = ar0 + koff + k4s * 4;
    const float* aq1 = ar1 + koff + k4s * 4;
    const int dA0 = 4096 + (rr << 6) + ((k4s ^ (rr & 7)) << 2);
    const int dA1 = 4096 + ((rr + 16) << 6) + ((k4s ^ (rr & 7)) << 2);

    float acc[8][8] = {};
    if (cohA)
        gemm_core64<true>(wq0, wq1, wq2, wq3, aq0, aq1,
                          dW0, dW1, dW2, dW3, dA0, dA1, nch, lds, tid, acc);
    else
        gemm_core64<false>(wq0, wq1, wq2, wq3, aq0, aq1,
                           dW0, dW1, dW2, dW3, dA0, dA1, nch, lds, tid, acc);
    reduce_totl(lds, tid, acc);

    {
        const int b = tid >> 3, seg = tid & 7;
        float* gout = gbuf + (size_t)kslice * B_ * NR_
                    + (size_t)b * NR_ + nout + seg * 8;
        f32x4 x0 = *(f32x4*)&lds[b * 68 + seg * 8];
        f32x4 x1 = *(f32x4*)&lds[b * 68 + seg * 8 + 4];
        st_cohx4(gout, x0);
        st_cohx4(gout + 4, x1);
    }
}

// Combine phase: 32768 elems over 256 blocks x 128 active threads.
__device__ __forceinline__ void combine_phase(
    int blk, int tid, const float* gbuf,
    const float* bih, const float* bhh,
    const float* hprev, float* hnew)
{
    if (tid >= 128) return;
    const int idx = blk * 128 + tid;          // 0..32767
    const int b = idx >> 10, i = idx & 1023;
    const float* gb0 = gbuf + (size_t)b * NR_;
    const float* gb1 = gbuf + (size_t)(B_ + b) * NR_;
    const float gir = ld_cohf(gb0 + i)              + ld_cohf(gb1 + i);
    const float giz = ld_cohf(gb0 + H_ + i)         + ld_cohf(gb1 + H_ + i);
    const float gin = ld_cohf(gb0 + 2*H_ + i)       + ld_cohf(gb1 + 2*H_ + i);
    const float ghr = ld_cohf(gb0 + NG_ + i)        + ld_cohf(gb1 + NG_ + i);
    const float ghz = ld_cohf(gb0 + NG_ + H_ + i)   + ld_cohf(gb1 + NG_ + H_ + i);
    const float ghn = ld_cohf(gb0 + NG_ + 2*H_ + i) + ld_cohf(gb1 + NG_ + 2*H_ + i);
    const float Sr = gir + ghr + bih[i] + bhh[i];
    const float Sz = giz + ghz + bih[H_ + i] + bhh[H_ + i];
    const float rr = 1.f / (1.f + expf(-Sr));
    const float zz = 1.f / (1.f + expf(-Sz));
    const float nn = tanhf(gin + bih[2*H_ + i] + rr * (ghn + bhh[2*H_ + i]));
    const float hp = ld_cohf(hprev + (size_t)b * H_ + i);
    st_cohf(hnew + (size_t)b * H_ + i, (1.f - zz) * nn + zz * hp);
}

// Logits phase body (r12-verbatim math). blk in [0,250).
__device__ __forceinline__ void logits_phase(
    int blk, int tid, float* lds,
    const float* h1, const float* Wout, const float* bout,
    float* out_t, u64* tokpk_t)
{
    const int v0 = blk * 64;
    const int k4s = tid & 15;
    const int rr  = tid >> 4;

    const float *wq0, *wq1, *wq2, *wq3;
    int dW0, dW1, dW2, dW3;
    {
        const int r0 = rr, r1 = 16 + rr, r2 = 32 + rr, r3 = 48 + rr;
        wq0 = Wout + (size_t)(v0 + r0) * H_ + k4s * 4;
        wq1 = Wout + (size_t)(v0 + r1) * H_ + k4s * 4;
        wq2 = Wout + (size_t)(v0 + r2) * H_ + k4s * 4;
        wq3 = Wout + (size_t)(v0 + r3) * H_ + k4s * 4;
        dW0 = (r0 << 6) + ((k4s ^ (r0 & 7)) << 2);
        dW1 = (r1 << 6) + ((k4s ^ (r1 & 7)) << 2);
        dW2 = (r2 << 6) + ((k4s ^ (r2 & 7)) << 2);
        dW3 = (r3 << 6) + ((k4s ^ (r3 & 7)) << 2);
    }
    const float* aq0 = h1 + (size_t)rr * H_ + k4s * 4;
    const float* aq1 = h1 + (size_t)(rr + 16) * H_ + k4s * 4;
    const int dA0 = 4096 + (rr << 6) + ((k4s ^ (rr & 7)) << 2);
    const int dA1 = 4096 + ((rr + 16) << 6) + ((k4s ^ (rr & 7)) << 2);

    float acc[8][8] = {};
    gemm_core64<true>(wq0, wq1, wq2, wq3, aq0, aq1,
                      dW0, dW1, dW2, dW3, dA0, dA1, H_ >> 6, lds, tid, acc);
    reduce_totl(lds, tid, acc);

    u64* am = (u64*)(lds + 2176);            // [32][8], after totl
    {
        const int b = tid >> 3, seg = tid & 7;
        f32x4 x0 = *(f32x4*)&lds[b * 68 + seg * 8];
        f32x4 x1 = *(f32x4*)&lds[b * 68 + seg * 8 + 4];
        f32x4 bo0 = *(const f32x4*)(bout + v0 + seg * 8);
        f32x4 bo1 = *(const f32x4*)(bout + v0 + seg * 8 + 4);
        x0 += bo0; x1 += bo1;
        __builtin_nontemporal_store(
            x0, (f32x4*)(out_t + (size_t)b * V_ + v0 + seg * 8));
        __builtin_nontemporal_store(
            x1, (f32x4*)(out_t + (size_t)b * V_ + v0 + seg * 8 + 4));
        const int vb = v0 + seg * 8;
        float vals[8] = {x0.x, x0.y, x0.z, x0.w, x1.x, x1.y, x1.z, x1.w};
        u64 best = 0ull;
        #pragma unroll
        for (int i = 0; i < 8; i++) {
            u64 p = ((u64)fkey(vals[i]) << 32)
                  | (u64)(0xFFFFFFFFu - (unsigned)(vb + i));
            best = p > best ? p : best;
        }
        am[b * 8 + seg] = best;
    }
    __syncthreads();
    if (tid < 32) {
        u64 best = 0ull;
        #pragma unroll
        for (int q = 0; q < 8; q++) {
            u64 p = am[tid * 8 + q];
            best = p > best ? p : best;
        }
        atomicMax(&tokpk_t[(size_t)tid * TPAD_], best);
    }
}

// ---------------------------------------------------------------------------
// Persistent decoder: whole T=64 decode in one kernel. Grid = 256 blocks
// (1/CU forced by 82KB LDS), 5 hierarchical grid barriers per step.
// ---------------------------------------------------------------------------
__global__ __launch_bounds__(256) void decoder_kernel(
    const float* __restrict__ embed,
    const float* __restrict__ Wih0, const float* __restrict__ Whh0,
    const float* __restrict__ bih0, const float* __restrict__ bhh0,
    const float* __restrict__ Wih1, const float* __restrict__ Whh1,
    const float* __restrict__ bih1, const float* __restrict__ bhh1,
    const float* __restrict__ Wout, const float* __restrict__ bout,
    float* __restrict__ out,
    float* __restrict__ h0buf, float* __restrict__ h1buf,
    float* __restrict__ gbuf, u64* __restrict__ tokpk,
    unsigned* __restrict__ bar)
{
    __shared__ float lds[20608];   // 82,432 B > 160KB/2: forces 1 block/CU
    const int blk = blockIdx.x;
    const int tid = threadIdx.x;
    const int BH = B_ * H_;
    unsigned bk = 0;

    for (int t = 0; t < T_; t++) {
        const int rp = t & 1, wp2 = (t + 1) & 1;
        const u64* tokprev = tokpk + (size_t)(t > 0 ? t - 1 : 0) * B_ * TPAD_;

        if (blk < 192)
            gru_gemm_phase(blk, tid, lds, Wih0, Whh0, E_, nullptr, 0,
                           embed, tokprev, t, /*tmode=*/1,
                           h0buf + (size_t)rp * BH, gbuf);
        gbar(bar, ++bk);

        combine_phase(blk, tid, gbuf, bih0, bhh0,
                      h0buf + (size_t)rp * BH, h0buf + (size_t)wp2 * BH);
        gbar(bar, ++bk);

        if (blk < 192)
            gru_gemm_phase(blk, tid, lds, Wih1, Whh1, H_,
                           h0buf + (size_t)wp2 * BH, H_,
                           embed, tokprev, 0, /*tmode=*/0,
                           h1buf + (size_t)rp * BH, gbuf);
        gbar(bar, ++bk);

        combine_phase(blk, tid, gbuf, bih1, bhh1,
                      h1buf + (size_t)rp * BH, h1buf + (size_t)wp2 * BH);
        gbar(bar, ++bk);

        if (blk < 250)
            logits_phase(blk, tid, lds, h1buf + (size_t)wp2 * BH, Wout, bout,
                         out + (size_t)t * B_ * V_,
                         tokpk + (size_t)t * B_ * TPAD_);
        gbar(bar, ++bk);
    }
}

extern "C" void kernel_launch(void* const* d_in, const int* in_sizes, int n_in,
                              void* d_out, int out_size, void* d_ws, size_t ws_size,
                              hipStream_t stream) {
    const float* hidden = (const float*)d_in[0];
    const float* embed  = (const float*)d_in[1];
    const float* Wih0   = (const float*)d_in[2];
    const float* Whh0   = (const float*)d_in[3];
    const float* bih0   = (const float*)d_in[4];
    const float* bhh0   = (const float*)d_in[5];
    const float* Wih1   = (const float*)d_in[6];
    const float* Whh1   = (const float*)d_in[7];
    const float* bih1   = (const float*)d_in[8];
    const float* bhh1   = (const float*)d_in[9];
    const float* Wout   = (const float*)d_in[10];
    const float* bout   = (const float*)d_in[11];
    float* out = (float*)d_out;

    const int BH = B_ * H_;
    float* ws = (float*)d_ws;
    float* h0buf = ws;                        // [2][B][H]
    float* h1buf = ws + 2 * BH;               // [2][B][H]
    float* gbuf  = ws + 4 * BH;               // [2][B][NR_]
    u64* tokpk = (u64*)(ws + 4 * BH + 2 * B_ * NR_);  // [T][B*TPAD_]
    unsigned* bar = (unsigned*)(tokpk + (size_t)T_ * B_ * TPAD_);  // [288]

    init_kernel<<<128, 256, 0, stream>>>(hidden, h0buf, h1buf, tokpk, bar);

    decoder_kernel<<<NBLK_, 256, 0, stream>>>(
        embed, Wih0, Whh0, bih0, bhh0, Wih1, Whh1, bih1, bhh1,
        Wout, bout, out, h0buf, h1buf, gbuf, tokpk, bar);
}

// Round 16
// 4041.162 us; speedup vs baseline: 4.0817x; 1.0389x over previous
//
#include <hip/hip_runtime.h>
#include <stdint.h>

#define V_ 16000
#define E_ 512
#define H_ 1024
#define B_ 32
#define T_ 64
#define NG_ 3072        // 3*H rows per weight matrix
#define NR_ 6144        // virtual rows in gru gemm (ih + hh)
#define TPAD_ 8         // u64 stride per batch token slot
#define NBLK_ 256       // persistent grid = #CUs

typedef float f32x4 __attribute__((ext_vector_type(4)));
typedef unsigned long long u64;

__device__ __forceinline__ unsigned int fkey(float f) {
    unsigned int u = __float_as_uint(f);
    return (u & 0x80000000u) ? ~u : (u | 0x80000000u);
}

// ---- device-coherent (agent-scope, sc1) access helpers -------------------
__device__ __forceinline__ f32x4 ld_cohx4(const float* p) {
    u64 lo = __hip_atomic_load((const u64*)p,       __ATOMIC_RELAXED,
                               __HIP_MEMORY_SCOPE_AGENT);
    u64 hi = __hip_atomic_load(((const u64*)p) + 1, __ATOMIC_RELAXED,
                               __HIP_MEMORY_SCOPE_AGENT);
    union { u64 q[2]; f32x4 v; } u;
    u.q[0] = lo; u.q[1] = hi;
    return u.v;
}
__device__ __forceinline__ void st_cohx4(float* p, f32x4 v) {
    union { u64 q[2]; f32x4 v; } u;
    u.v = v;
    __hip_atomic_store((u64*)p,       u.q[0], __ATOMIC_RELAXED,
                       __HIP_MEMORY_SCOPE_AGENT);
    __hip_atomic_store(((u64*)p) + 1, u.q[1], __ATOMIC_RELAXED,
                       __HIP_MEMORY_SCOPE_AGENT);
}
__device__ __forceinline__ float ld_cohf(const float* p) {
    return __hip_atomic_load(p, __ATOMIC_RELAXED, __HIP_MEMORY_SCOPE_AGENT);
}
__device__ __forceinline__ void st_cohf(float* p, float v) {
    __hip_atomic_store(p, v, __ATOMIC_RELAXED, __HIP_MEMORY_SCOPE_AGENT);
}
__device__ __forceinline__ u64 ld_cohu64(const u64* p) {
    return __hip_atomic_load(p, __ATOMIC_RELAXED, __HIP_MEMORY_SCOPE_AGENT);
}

// Hierarchical monotonic grid barrier with BROADCAST-TREE release.
// bar layout (u32): l0[g] at [g*16] (g<16, 64B lines); root at [256];
// global gen at [272]; per-group ggen[g] at [512 + g*16] (64B lines).
// Arrival: <=16 RMWs per l0 (parallel across groups) + <=16 on root.
// Release: group-last (awake) polls global gen (<=16 pollers), then stores
// k to its group's ggen; members poll ggen (<=15 pollers/line). Max
// pollers per line 255 -> 16: kills the CP poll-queue serialization.
__device__ __forceinline__ void gbar(unsigned* bar, unsigned k) {
    __syncthreads();   // drains vmcnt: block's coherent stores are at CP
    if (threadIdx.x == 0) {
        const unsigned g = (unsigned)blockIdx.x >> 4;
        unsigned* l0   = bar + (g << 4);
        unsigned* root = bar + 256;
        unsigned* gen  = bar + 272;
        unsigned* ggen = bar + 512 + (g << 4);
        unsigned a = __hip_atomic_fetch_add(l0, 1u, __ATOMIC_RELAXED,
                                            __HIP_MEMORY_SCOPE_AGENT);
        if (a == k * 16u - 1u) {           // last of my 16-block group
            unsigned r = __hip_atomic_fetch_add(root, 1u, __ATOMIC_RELAXED,
                                                __HIP_MEMORY_SCOPE_AGENT);
            if (r == k * 16u - 1u) {       // last group: global release
                __hip_atomic_fetch_add(gen, 1u, __ATOMIC_RELEASE,
                                       __HIP_MEMORY_SCOPE_AGENT);
            } else {
                while (__hip_atomic_load(gen, __ATOMIC_RELAXED,
                                         __HIP_MEMORY_SCOPE_AGENT) < k)
                    __builtin_amdgcn_s_sleep(2);
            }
            __hip_atomic_store(ggen, k, __ATOMIC_RELAXED,
                               __HIP_MEMORY_SCOPE_AGENT);
        } else {
            while (__hip_atomic_load(ggen, __ATOMIC_RELAXED,
                                     __HIP_MEMORY_SCOPE_AGENT) < k)
                __builtin_amdgcn_s_sleep(2);
        }
    }
    __syncthreads();
}

__global__ void init_kernel(const float* __restrict__ hidden,
                            float* __restrict__ h0, float* __restrict__ h1,
                            u64* __restrict__ tokpk, unsigned* __restrict__ bar) {
    int idx = blockIdx.x * blockDim.x + threadIdx.x;
    if (idx < B_ * H_) {
        h0[idx] = hidden[idx];
        h1[idx] = hidden[B_ * H_ + idx];
    }
    if (idx < T_ * B_ * TPAD_) tokpk[idx] = 0ull;
    if (idx < 1024) bar[idx] = 0u;
}

// ---------------------------------------------------------------------------
// r12-proven 64-row x 32-batch streamed GEMM core, 256 threads, acc[8][8].
// CA: A-operand loaded device-coherent (h-buffers) vs plain (embed/Wout...).
// ---------------------------------------------------------------------------
template<bool CA>
__device__ __forceinline__ void gemm_core64(
    const float* wq0, const float* wq1, const float* wq2, const float* wq3,
    const float* aq0, const float* aq1,
    int dW0, int dW1, int dW2, int dW3, int dA0, int dA1,
    int nch, float* lds, int tid, float acc[8][8])
{
    const int ks = tid >> 5, pos = tid & 31;
    const int rg = pos >> 2, bgp = pos & 3;

    f32x4 w0 = *(const f32x4*)wq0, w1 = *(const f32x4*)wq1;
    f32x4 w2 = *(const f32x4*)wq2, w3 = *(const f32x4*)wq3;
    f32x4 a0 = CA ? ld_cohx4(aq0) : *(const f32x4*)aq0;
    f32x4 a1 = CA ? ld_cohx4(aq1) : *(const f32x4*)aq1;
    *(f32x4*)&lds[dW0] = w0; *(f32x4*)&lds[dW1] = w1;
    *(f32x4*)&lds[dW2] = w2; *(f32x4*)&lds[dW3] = w3;
    *(f32x4*)&lds[dA0] = a0; *(f32x4*)&lds[dA1] = a1;
    __syncthreads();

    int cur = 0;
    for (int c = 0; c < nch; c++) {
        if (c + 1 < nch) {
            const int o = (c + 1) << 6;
            w0 = *(const f32x4*)(wq0 + o); w1 = *(const f32x4*)(wq1 + o);
            w2 = *(const f32x4*)(wq2 + o); w3 = *(const f32x4*)(wq3 + o);
            a0 = CA ? ld_cohx4(aq0 + o) : *(const f32x4*)(aq0 + o);
            a1 = CA ? ld_cohx4(aq1 + o) : *(const f32x4*)(aq1 + o);
        }
        const float* Wb = &lds[cur * 6144];
        const float* Ab = Wb + 4096;
        #pragma unroll
        for (int kk = 0; kk < 2; kk++) {
            const int k4 = ks * 2 + kk;
            f32x4 ww[8], ha[8];
            #pragma unroll
            for (int vi = 0; vi < 8; vi++) {
                const int row = rg + 8 * vi;           // row&7 == rg
                ww[vi] = *(const f32x4*)&Wb[(row << 6) + ((k4 ^ rg) << 2)];
            }
            #pragma unroll
            for (int j = 0; j < 8; j++) {
                const int br = bgp + 4 * j;
                ha[j] = *(const f32x4*)&Ab[(br << 6) + ((k4 ^ (br & 7)) << 2)];
            }
            #pragma unroll
            for (int vi = 0; vi < 8; vi++)
                #pragma unroll
                for (int j = 0; j < 8; j++)
                    acc[vi][j] += ww[vi].x*ha[j].x + ww[vi].y*ha[j].y
                                + ww[vi].z*ha[j].z + ww[vi].w*ha[j].w;
        }
        if (c + 1 < nch) {
            float* L = &lds[(cur ^ 1) * 6144];
            *(f32x4*)&L[dW0] = w0; *(f32x4*)&L[dW1] = w1;
            *(f32x4*)&L[dW2] = w2; *(f32x4*)&L[dW3] = w3;
            *(f32x4*)&L[dA0] = a0; *(f32x4*)&L[dA1] = a1;
        }
        __syncthreads();
        cur ^= 1;
    }
}

__device__ __forceinline__ void reduce_totl(float* lds, int tid, float acc[8][8])
{
    const int ks = tid >> 5, pos = tid & 31;
    {
        float* dst = &lds[(ks * 32 + pos) * 68];
        #pragma unroll
        for (int vi = 0; vi < 8; vi++) {
            f32x4 p0 = {acc[vi][0], acc[vi][1], acc[vi][2], acc[vi][3]};
            f32x4 p1 = {acc[vi][4], acc[vi][5], acc[vi][6], acc[vi][7]};
            *(f32x4*)&dst[vi * 8]     = p0;
            *(f32x4*)&dst[vi * 8 + 4] = p1;
        }
    }
    __syncthreads();
    const int vi2 = tid >> 5, pos2 = tid & 31;
    f32x4 s0 = {0.f, 0.f, 0.f, 0.f}, s1 = {0.f, 0.f, 0.f, 0.f};
    #pragma unroll
    for (int k = 0; k < 8; k++) {
        const float* src = &lds[(k * 32 + pos2) * 68 + vi2 * 8];
        s0 += *(const f32x4*)src;
        s1 += *(const f32x4*)(src + 4);
    }
    __syncthreads();
    const int row = (pos2 >> 2) + 8 * vi2;   // 0..63
    const int bb  = pos2 & 3;                // batch = bb + 4*j
    lds[(bb +  0) * 68 + row] = s0.x;
    lds[(bb +  4) * 68 + row] = s0.y;
    lds[(bb +  8) * 68 + row] = s0.z;
    lds[(bb + 12) * 68 + row] = s0.w;
    lds[(bb + 16) * 68 + row] = s1.x;
    lds[(bb + 20) * 68 + row] = s1.y;
    lds[(bb + 24) * 68 + row] = s1.z;
    lds[(bb + 28) * 68 + row] = s1.w;
    __syncthreads();
}

// GRU GEMM phase body (r12-verbatim math). blk in [0,192).
__device__ __forceinline__ void gru_gemm_phase(
    int blk0, int tid, float* lds,
    const float* Wih, const float* Whh, int Kih,
    const float* xbase, int xld,
    const float* embed, const u64* tokprev, int t, int tmode,
    const float* hprev, float* gbuf)
{
    const int kslice = blk0 >= 96 ? 1 : 0;
    const int tile = blk0 - kslice * 96;
    const int k4s = tid & 15;
    const int rr  = tid >> 4;                // 0..15

    const float* Wbase; int K, n0, nout;
    const float *ar0, *ar1;
    bool cohA;
    if (tile < 48) {
        n0 = tile * 64; nout = n0; Wbase = Wih; K = Kih;
        if (tmode) {
            int tok0 = 0, tok1 = 0;
            if (t > 0) {
                tok0 = (int)(0xFFFFFFFFu -
                       (unsigned)(ld_cohu64(&tokprev[(size_t)rr * TPAD_]) & 0xFFFFFFFFull));
                tok1 = (int)(0xFFFFFFFFu -
                       (unsigned)(ld_cohu64(&tokprev[(size_t)(rr + 16) * TPAD_]) & 0xFFFFFFFFull));
            }
            ar0 = embed + (size_t)tok0 * Kih;
            ar1 = embed + (size_t)tok1 * Kih;
            cohA = false;                    // embed is read-only
        } else {
            ar0 = xbase + (size_t)rr * xld;
            ar1 = xbase + (size_t)(rr + 16) * xld;
            cohA = true;                     // h0' written by other blocks
        }
    } else {
        n0 = (tile - 48) * 64; nout = NG_ + n0; Wbase = Whh; K = H_;
        ar0 = hprev + (size_t)rr * H_;
        ar1 = hprev + (size_t)(rr + 16) * H_;
        cohA = true;
    }
    const int koff = kslice * (K >> 1);
    const int nch  = K >> 7;                 // 4 or 8 chunks

    const float *wq0, *wq1, *wq2, *wq3;
    int dW0, dW1, dW2, dW3;
    {
        const int r0 = rr, r1 = 16 + rr, r2 = 32 + rr, r3 = 48 + rr;
        wq0 = Wbase + (size_t)(n0 + r0) * K + koff + k4s * 4;
        wq1 = Wbase + (size_t)(n0 + r1) * K + koff + k4s * 4;
        wq2 = Wbase + (size_t)(n0 + r2) * K + koff + k4s * 4;
        wq3 = Wbase + (size_t)(n0 + r3) * K + koff + k4s * 4;
        dW0 = (r0 << 6) + ((k4s ^ (r0 & 7)) << 2);
        dW1 = (r1 << 6) + ((k4s ^ (r1 & 7)) << 2);
        dW2 = (r2 << 6) + ((k4s ^ (r2 & 7)) << 2);
        dW3 = (r3 << 6) + ((k4s ^ (r3 & 7)) << 2);
    }
    const float* aq0 = ar0 + koff + k4s * 4;
    const float* aq1 = ar1 + koff + k4s * 4;
    const int dA0 = 4096 + (rr << 6) + ((k4s ^ (rr & 7)) << 2);
    const int dA1 = 4096 + ((rr + 16) << 6) + ((k4s ^ (rr & 7)) << 2);

    float acc[8][8] = {};
    if (cohA)
        gemm_core64<true>(wq0, wq1, wq2, wq3, aq0, aq1,
                          dW0, dW1, dW2, dW3, dA0, dA1, nch, lds, tid, acc);
    else
        gemm_core64<false>(wq0, wq1, wq2, wq3, aq0, aq1,
                           dW0, dW1, dW2, dW3, dA0, dA1, nch, lds, tid, acc);
    reduce_totl(lds, tid, acc);

    {
        const int b = tid >> 3, seg = tid & 7;
        float* gout = gbuf + (size_t)kslice * B_ * NR_
                    + (size_t)b * NR_ + nout + seg * 8;
        f32x4 x0 = *(f32x4*)&lds[b * 68 + seg * 8];
        f32x4 x1 = *(f32x4*)&lds[b * 68 + seg * 8 + 4];
        st_cohx4(gout, x0);
        st_cohx4(gout + 4, x1);
    }
}

// Combine phase: 32768 elems over 256 blocks x 128 active threads.
__device__ __forceinline__ void combine_phase(
    int blk, int tid, const float* gbuf,
    const float* bih, const float* bhh,
    const float* hprev, float* hnew)
{
    if (tid >= 128) return;
    const int idx = blk * 128 + tid;          // 0..32767
    const int b = idx >> 10, i = idx & 1023;
    const float* gb0 = gbuf + (size_t)b * NR_;
    const float* gb1 = gbuf + (size_t)(B_ + b) * NR_;
    const float gir = ld_cohf(gb0 + i)              + ld_cohf(gb1 + i);
    const float giz = ld_cohf(gb0 + H_ + i)         + ld_cohf(gb1 + H_ + i);
    const float gin = ld_cohf(gb0 + 2*H_ + i)       + ld_cohf(gb1 + 2*H_ + i);
    const float ghr = ld_cohf(gb0 + NG_ + i)        + ld_cohf(gb1 + NG_ + i);
    const float ghz = ld_cohf(gb0 + NG_ + H_ + i)   + ld_cohf(gb1 + NG_ + H_ + i);
    const float ghn = ld_cohf(gb0 + NG_ + 2*H_ + i) + ld_cohf(gb1 + NG_ + 2*H_ + i);
    const float Sr = gir + ghr + bih[i] + bhh[i];
    const float Sz = giz + ghz + bih[H_ + i] + bhh[H_ + i];
    const float rr = 1.f / (1.f + expf(-Sr));
    const float zz = 1.f / (1.f + expf(-Sz));
    const float nn = tanhf(gin + bih[2*H_ + i] + rr * (ghn + bhh[2*H_ + i]));
    const float hp = ld_cohf(hprev + (size_t)b * H_ + i);
    st_cohf(hnew + (size_t)b * H_ + i, (1.f - zz) * nn + zz * hp);
}

// Logits phase body (r12-verbatim math). blk in [0,250).
__device__ __forceinline__ void logits_phase(
    int blk, int tid, float* lds,
    const float* h1, const float* Wout, const float* bout,
    float* out_t, u64* tokpk_t)
{
    const int v0 = blk * 64;
    const int k4s = tid & 15;
    const int rr  = tid >> 4;

    const float *wq0, *wq1, *wq2, *wq3;
    int dW0, dW1, dW2, dW3;
    {
        const int r0 = rr, r1 = 16 + rr, r2 = 32 + rr, r3 = 48 + rr;
        wq0 = Wout + (size_t)(v0 + r0) * H_ + k4s * 4;
        wq1 = Wout + (size_t)(v0 + r1) * H_ + k4s * 4;
        wq2 = Wout + (size_t)(v0 + r2) * H_ + k4s * 4;
        wq3 = Wout + (size_t)(v0 + r3) * H_ + k4s * 4;
        dW0 = (r0 << 6) + ((k4s ^ (r0 & 7)) << 2);
        dW1 = (r1 << 6) + ((k4s ^ (r1 & 7)) << 2);
        dW2 = (r2 << 6) + ((k4s ^ (r2 & 7)) << 2);
        dW3 = (r3 << 6) + ((k4s ^ (r3 & 7)) << 2);
    }
    const float* aq0 = h1 + (size_t)rr * H_ + k4s * 4;
    const float* aq1 = h1 + (size_t)(rr + 16) * H_ + k4s * 4;
    const int dA0 = 4096 + (rr << 6) + ((k4s ^ (rr & 7)) << 2);
    const int dA1 = 4096 + ((rr + 16) << 6) + ((k4s ^ (rr & 7)) << 2);

    float acc[8][8] = {};
    gemm_core64<true>(wq0, wq1, wq2, wq3, aq0, aq1,
                      dW0, dW1, dW2, dW3, dA0, dA1, H_ >> 6, lds, tid, acc);
    reduce_totl(lds, tid, acc);

    u64* am = (u64*)(lds + 2176);            // [32][8], after totl
    {
        const int b = tid >> 3, seg = tid & 7;
        f32x4 x0 = *(f32x4*)&lds[b * 68 + seg * 8];
        f32x4 x1 = *(f32x4*)&lds[b * 68 + seg * 8 + 4];
        f32x4 bo0 = *(const f32x4*)(bout + v0 + seg * 8);
        f32x4 bo1 = *(const f32x4*)(bout + v0 + seg * 8 + 4);
        x0 += bo0; x1 += bo1;
        __builtin_nontemporal_store(
            x0, (f32x4*)(out_t + (size_t)b * V_ + v0 + seg * 8));
        __builtin_nontemporal_store(
            x1, (f32x4*)(out_t + (size_t)b * V_ + v0 + seg * 8 + 4));
        const int vb = v0 + seg * 8;
        float vals[8] = {x0.x, x0.y, x0.z, x0.w, x1.x, x1.y, x1.z, x1.w};
        u64 best = 0ull;
        #pragma unroll
        for (int i = 0; i < 8; i++) {
            u64 p = ((u64)fkey(vals[i]) << 32)
                  | (u64)(0xFFFFFFFFu - (unsigned)(vb + i));
            best = p > best ? p : best;
        }
        am[b * 8 + seg] = best;
    }
    __syncthreads();
    if (tid < 32) {
        u64 best = 0ull;
        #pragma unroll
        for (int q = 0; q < 8; q++) {
            u64 p = am[tid * 8 + q];
            best = p > best ? p : best;
        }
        atomicMax(&tokpk_t[(size_t)tid * TPAD_], best);
    }
}

// ---------------------------------------------------------------------------
// Persistent decoder: whole T=64 decode in one kernel. Grid = 256 blocks
// (1/CU forced by 82KB LDS), 5 broadcast-tree grid barriers per step.
// ---------------------------------------------------------------------------
__global__ __launch_bounds__(256) void decoder_kernel(
    const float* __restrict__ embed,
    const float* __restrict__ Wih0, const float* __restrict__ Whh0,
    const float* __restrict__ bih0, const float* __restrict__ bhh0,
    const float* __restrict__ Wih1, const float* __restrict__ Whh1,
    const float* __restrict__ bih1, const float* __restrict__ bhh1,
    const float* __restrict__ Wout, const float* __restrict__ bout,
    float* __restrict__ out,
    float* __restrict__ h0buf, float* __restrict__ h1buf,
    float* __restrict__ gbuf, u64* __restrict__ tokpk,
    unsigned* __restrict__ bar)
{
    __shared__ float lds[20608];   // 82,432 B > 160KB/2: forces 1 block/CU
    const int blk = blockIdx.x;
    const int tid = threadIdx.x;
    const int BH = B_ * H_;
    unsigned bk = 0;

    for (int t = 0; t < T_; t++) {
        const int rp = t & 1, wp2 = (t + 1) & 1;
        const u64* tokprev = tokpk + (size_t)(t > 0 ? t - 1 : 0) * B_ * TPAD_;

        if (blk < 192)
            gru_gemm_phase(blk, tid, lds, Wih0, Whh0, E_, nullptr, 0,
                           embed, tokprev, t, /*tmode=*/1,
                           h0buf + (size_t)rp * BH, gbuf);
        gbar(bar, ++bk);

        combine_phase(blk, tid, gbuf, bih0, bhh0,
                      h0buf + (size_t)rp * BH, h0buf + (size_t)wp2 * BH);
        gbar(bar, ++bk);

        if (blk < 192)
            gru_gemm_phase(blk, tid, lds, Wih1, Whh1, H_,
                           h0buf + (size_t)wp2 * BH, H_,
                           embed, tokprev, 0, /*tmode=*/0,
                           h1buf + (size_t)rp * BH, gbuf);
        gbar(bar, ++bk);

        combine_phase(blk, tid, gbuf, bih1, bhh1,
                      h1buf + (size_t)rp * BH, h1buf + (size_t)wp2 * BH);
        gbar(bar, ++bk);

        if (blk < 250)
            logits_phase(blk, tid, lds, h1buf + (size_t)wp2 * BH, Wout, bout,
                         out + (size_t)t * B_ * V_,
                         tokpk + (size_t)t * B_ * TPAD_);
        gbar(bar, ++bk);
    }
}

extern "C" void kernel_launch(void* const* d_in, const int* in_sizes, int n_in,
                              void* d_out, int out_size, void* d_ws, size_t ws_size,
                              hipStream_t stream) {
    const float* hidden = (const float*)d_in[0];
    const float* embed  = (const float*)d_in[1];
    const float* Wih0   = (const float*)d_in[2];
    const float* Whh0   = (const float*)d_in[3];
    const float* bih0   = (const float*)d_in[4];
    const float* bhh0   = (const float*)d_in[5];
    const float* Wih1   = (const float*)d_in[6];
    const float* Whh1   = (const float*)d_in[7];
    const float* bih1   = (const float*)d_in[8];
    const float* bhh1   = (const float*)d_in[9];
    const float* Wout   = (const float*)d_in[10];
    const float* bout   = (const float*)d_in[11];
    float* out = (float*)d_out;

    const int BH = B_ * H_;
    float* ws = (float*)d_ws;
    float* h0buf = ws;                        // [2][B][H]
    float* h1buf = ws + 2 * BH;               // [2][B][H]
    float* gbuf  = ws + 4 * BH;               // [2][B][NR_]
    u64* tokpk = (u64*)(ws + 4 * BH + 2 * B_ * NR_);  // [T][B*TPAD_]
    unsigned* bar = (unsigned*)(tokpk + (size_t)T_ * B_ * TPAD_);  // [1024]

    init_kernel<<<128, 256, 0, stream>>>(hidden, h0buf, h1buf, tokpk, bar);

    decoder_kernel<<<NBLK_, 256, 0, stream>>>(
        embed, Wih0, Whh0, bih0, bhh0, Wih1, Whh1, bih1, bhh1,
        Wout, bout, out, h0buf, h1buf, gbuf, tokpk, bar);
}